// Round 3
// baseline (312.031 us; speedup 1.0000x reference)
//
#include <hip/hip_runtime.h>
#include <hip/hip_bf16.h>
#include <stdint.h>

#define B_SZ 4096
#define D_SZ 2048

typedef __attribute__((ext_vector_type(4))) float f32x4;
typedef __attribute__((ext_vector_type(8))) __bf16 bf16x8;
typedef __attribute__((ext_vector_type(4))) unsigned short u16x4;
typedef unsigned short u16;

static constexpr long BD = (long)B_SZ * D_SZ;   // 8388608
static constexpr long DD = (long)D_SZ * D_SZ;   // 4194304

__device__ __forceinline__ u16 f2bf(float f) {
  union { float f; unsigned int u; } c; c.f = f;
  unsigned int u = c.u;
  u = (u + 0x7fffu + ((u >> 16) & 1u)) >> 16;
  return (u16)u;
}
__device__ __forceinline__ float bf2f(u16 h) {
  union { unsigned int u; float f; } c; c.u = ((unsigned int)h) << 16;
  return c.f;
}

// ---------------------------------------------------------------- convert
__global__ __launch_bounds__(256) void k_convert(
    const float* __restrict__ x,  const float* __restrict__ wr,
    const float* __restrict__ wk, const float* __restrict__ wv,
    const float* __restrict__ wo,
    u16* __restrict__ Xb, u16* __restrict__ W3b, u16* __restrict__ Wob) {
  long i = ((long)blockIdx.x * 256 + threadIdx.x) * 4;
  const float* src; u16* dst; long so, dofs;
  if (i < BD)               { src = x;  so = i;            dst = Xb;  dofs = so; }
  else if (i < BD + DD)     { src = wr; so = i - BD;       dst = W3b; dofs = i - BD; }
  else if (i < BD + 2*DD)   { src = wk; so = i - BD - DD;  dst = W3b; dofs = i - BD; }
  else if (i < BD + 3*DD)   { src = wv; so = i - BD - 2*DD; dst = W3b; dofs = i - BD; }
  else                      { src = wo; so = i - BD - 3*DD; dst = Wob; dofs = so; }
  f32x4 v = *reinterpret_cast<const f32x4*>(src + so);
  u16x4 o;
  o[0] = f2bf(v[0]); o[1] = f2bf(v[1]); o[2] = f2bf(v[2]); o[3] = f2bf(v[3]);
  *reinterpret_cast<u16x4*>(dst + dofs) = o;
}

// ---------------------------------------------------------------- async global->LDS
__device__ __forceinline__ void gload16(const u16* g, const u16* l) {
  __builtin_amdgcn_global_load_lds(
      (const __attribute__((address_space(1))) unsigned int*)g,
      (__attribute__((address_space(3))) unsigned int*)l, 16, 0, 0);
}

#define FENCE asm volatile("" ::: "memory")
#define BAR do { FENCE; __builtin_amdgcn_s_barrier(); FENCE; } while (0)
#define VMC(n) asm volatile("s_waitcnt vmcnt(" #n ")" ::: "memory")

// ================================================================ 8-phase 256x256 GEMM
// C = A * B^T.  A:[M,K] bf16 rm, Bm:[N,K] bf16 rm. BK=64, 512 thr = 8 waves (2M x 4N).
// Trailing-issue schedule: each slot's ds_reads are issued in the PREVIOUS slot's
// tail (after its MFMAs, before the closing barrier) so LDS service overlaps
// barrier-skew + MFMA. vmcnt invariants identical to the verified round-2 stream.
template <bool OUT_BF16>
__global__ __launch_bounds__(512, 2) void k_gemm8(
    const u16* __restrict__ A, const u16* __restrict__ Bm,
    void* __restrict__ C, int M, int N, int K) {
  __shared__ __align__(16) u16 lds[65536];  // 128 KiB
  const int tid = threadIdx.x;
  const int l   = tid & 63;
  const int wv  = tid >> 6;   // 0..7
  const int wm  = wv >> 2;    // 0..1
  const int wn  = wv & 3;     // 0..3
  // XCD-aware swizzle (gridDim.x % 8 == 0): consecutive swz share the A row-panel
  const int tiles_n = N >> 8;
  const int nwg = gridDim.x;
  const int cpx = nwg >> 3;
  const int bid = (int)blockIdx.x;
  const int swz = (bid & 7) * cpx + (bid >> 3);
  const int bm = swz / tiles_n, bn = swz % tiles_n;
  const int NT = K >> 6;      // 64-wide K-tiles; NT even, >=4

  // ---- staging addressing (inverse-swizzled global source, linear LDS dest)
  const int gcol = (((l & 7) ^ (l >> 3)) << 3);       // element col, pre-swizzled
  const int grow = wv * 16 + (l >> 3);                // j=0 row within half (j=1: +8)
  const u16* Abase = A  + (long)(bm * 256 + grow) * K + gcol;
  const u16* Bbase = Bm + (long)(bn * 256 + grow) * K + gcol;
  const int stdst = wv * 1024;                        // u16 idx within region (+512 for j=1)

  // STAGE(t, hk): hk 0=B-h0, 1=B-h1, 2=A-h0, 3=A-h1  (2 loads/wave each)
  #define STAGE(t, hk) do {                                                  \
    const int  _h   = (hk) & 1;                                              \
    const bool _isA = (hk) >= 2;                                             \
    const u16* _g = (_isA ? Abase : Bbase) + (long)(_h * 128) * K + (long)(t) * 64; \
    u16* _d = &lds[((t) & 1) * 32768 + (_isA ? 0 : 16384) + _h * 8192 + stdst]; \
    gload16(_g, _d);                                                         \
    gload16(_g + 8 * (long)K, _d + 512);                                     \
  } while (0)

  // ---- read-side addressing (swizzled)
  const int rby  = (l & 15) * 128;                          // row byte
  const int obx0 = ((l >> 4) * 16) ^ ((l & 7) << 4);        // ks=0 byte-in-row
  int laneO[2];
  laneO[0] = (rby + obx0) >> 1;          // u16 idx
  laneO[1] = laneO[0] ^ 32;              // ks=1 (= byte ^ 64)

  f32x4 acc[8][4] = {};
  bf16x8 af[4][2], bf01[2][2], bf23[2][2];

  auto LDA = [&](int p, int mbase) {
#pragma unroll
    for (int mi = 0; mi < 4; ++mi)
#pragma unroll
      for (int ks = 0; ks < 2; ++ks)
        af[mi][ks] = *reinterpret_cast<const bf16x8*>(
            &lds[p * 32768 + wm * 8192 + (mbase + mi) * 1024 + laneO[ks]]);
  };
  auto LDB = [&](int p, int nbase, bf16x8 (&bf)[2][2]) {
#pragma unroll
    for (int ni = 0; ni < 2; ++ni)
#pragma unroll
      for (int ks = 0; ks < 2; ++ks)
        bf[ni][ks] = *reinterpret_cast<const bf16x8*>(
            &lds[p * 32768 + 16384 + wn * 4096 + (nbase + ni) * 1024 + laneO[ks]]);
  };
  // ks-outer: same-acc reuse distance = 8 MFMAs (dep-chain break)
  auto MQ = [&](int mbase, int nbase, bf16x8 (&bf)[2][2]) {
    __builtin_amdgcn_s_setprio(1);
#pragma unroll
    for (int ks = 0; ks < 2; ++ks)
#pragma unroll
      for (int mi = 0; mi < 4; ++mi)
#pragma unroll
        for (int ni = 0; ni < 2; ++ni)
          acc[mbase + mi][nbase + ni] = __builtin_amdgcn_mfma_f32_16x16x32_bf16(
              af[mi][ks], bf[ni][ks], acc[mbase + mi][nbase + ni], 0, 0, 0);
    __builtin_amdgcn_s_setprio(0);
  };

  // ---- prologue: tile0 fully + B-halves of tile1; 4 loads stay in flight;
  //      pre-issue S1's reads (af(0-3), bf01 of tile0)
  STAGE(0, 0); STAGE(0, 1); STAGE(0, 2); STAGE(0, 3);
  STAGE(1, 0); STAGE(1, 1);
  VMC(4); BAR;
  LDA(0, 0); LDB(0, 0, bf01);

  // ---- main loop: 2 K-tiles / iteration, 8 slots, trailing-issue reads
  int t = 0;
  for (; t + 3 < NT; t += 2) {
    // S1
    STAGE(t + 1, 2); BAR;
    MQ(0, 0, bf01); LDB(0, 2, bf23); BAR;
    // S2
    STAGE(t + 1, 3); BAR;
    MQ(0, 2, bf23); LDA(0, 4); BAR;
    // S3
    STAGE(t + 2, 0); BAR;
    MQ(4, 2, bf23); BAR;
    // S4
    STAGE(t + 2, 1); VMC(4); BAR;
    MQ(4, 0, bf01); LDA(1, 0); LDB(1, 0, bf01); BAR;
    // S5
    STAGE(t + 2, 2); BAR;
    MQ(0, 0, bf01); LDB(1, 2, bf23); BAR;
    // S6
    STAGE(t + 2, 3); BAR;
    MQ(0, 2, bf23); LDA(1, 4); BAR;
    // S7
    STAGE(t + 3, 0); BAR;
    MQ(4, 2, bf23); BAR;
    // S8
    STAGE(t + 3, 1); VMC(4); BAR;
    MQ(4, 0, bf01); LDA(0, 0); LDB(0, 0, bf01); BAR;
  }

  // ---- epilogue: tiles NT-2 (buf0), NT-1 (buf1)
  // E1
  STAGE(NT - 1, 2); BAR;
  MQ(0, 0, bf01); LDB(0, 2, bf23); BAR;
  // E2
  STAGE(NT - 1, 3); BAR;
  MQ(0, 2, bf23); LDA(0, 4); BAR;
  // E3
  MQ(4, 2, bf23); BAR;
  // E4
  VMC(0); BAR;
  MQ(4, 0, bf01); LDA(1, 0); LDB(1, 0, bf01); BAR;
  // E5
  MQ(0, 0, bf01); LDB(1, 2, bf23); BAR;
  // E6
  MQ(0, 2, bf23); LDA(1, 4); BAR;
  // E7
  MQ(4, 2, bf23);
  // E8
  MQ(4, 0, bf01);
  #undef STAGE

  // ---- C write: 16x16 frag layout col = l&15, row = (l>>4)*4 + reg
  const int rb = (l >> 4) * 4, cb = l & 15;
  const long Crow0 = (long)bm * 256 + wm * 128 + rb;
  const long Ccol0 = (long)bn * 256 + wn * 64 + cb;
#pragma unroll
  for (int mf = 0; mf < 8; ++mf)
#pragma unroll
    for (int nf = 0; nf < 4; ++nf)
#pragma unroll
      for (int r = 0; r < 4; ++r) {
        const long gr = Crow0 + mf * 16 + r;
        const long gc = Ccol0 + nf * 16;
        if constexpr (OUT_BF16)
          ((u16*)C)[gr * N + gc] = f2bf(acc[mf][nf][r]);
        else
          ((float*)C)[gr * N + gc] = acc[mf][nf][r];
      }
}

// ---------------------------------------------------------------- m97 128x128 GEMM (out-proj)
template <bool OUT_BF16>
__global__ __launch_bounds__(256) void k_gemm_bt(
    const u16* __restrict__ A, const u16* __restrict__ Bm,
    void* __restrict__ C, int M, int N, int K) {
  __shared__ __align__(16) u16 As[128 * 32];
  __shared__ __align__(16) u16 Bs[128 * 32];
  const int tid  = threadIdx.x;
  const int lane = tid & 63;
  const int wave = tid >> 6;
  const int bm = blockIdx.y, bn = blockIdx.x;
  const int wm = (wave >> 1) * 64, wn = (wave & 1) * 64;

  f32x4 acc[4][4] = {};

  const int row0 = tid >> 2;
  const int cole = (tid & 3) * 8;
  const u16* Ag = A + (long)(bm * 128 + row0) * K + cole;
  const u16* Bg = Bm + (long)(bn * 128 + row0) * K + cole;
  const u16* AsW = As + wave * 512;
  const u16* BsW = Bs + wave * 512;

  const int fr = lane & 15;
  const int fk = (lane >> 4) * 8;

  for (int k0 = 0; k0 < K; k0 += 32) {
    gload16(Ag + k0,           AsW);
    gload16(Ag + 64 * K + k0,  AsW + 2048);
    gload16(Bg + k0,           BsW);
    gload16(Bg + 64 * K + k0,  BsW + 2048);
    __syncthreads();

    bf16x8 af[4], bf[4];
#pragma unroll
    for (int mi = 0; mi < 4; ++mi)
      af[mi] = *reinterpret_cast<const bf16x8*>(&As[(wm + mi * 16 + fr) * 32 + fk]);
#pragma unroll
    for (int ni = 0; ni < 4; ++ni)
      bf[ni] = *reinterpret_cast<const bf16x8*>(&Bs[(wn + ni * 16 + fr) * 32 + fk]);
#pragma unroll
    for (int mi = 0; mi < 4; ++mi)
#pragma unroll
      for (int ni = 0; ni < 4; ++ni)
        acc[mi][ni] = __builtin_amdgcn_mfma_f32_16x16x32_bf16(af[mi], bf[ni], acc[mi][ni], 0, 0, 0);
    __syncthreads();
  }

  const int rb = (lane >> 4) * 4, cb = lane & 15;
  const long Crow0 = (long)bm * 128 + wm + rb;
  const long Ccol0 = (long)bn * 128 + wn + cb;
#pragma unroll
  for (int mi = 0; mi < 4; ++mi)
#pragma unroll
    for (int ni = 0; ni < 4; ++ni)
#pragma unroll
      for (int r = 0; r < 4; ++r) {
        const long gr = Crow0 + mi * 16 + r;
        const long gc = Ccol0 + ni * 16;
        if constexpr (OUT_BF16)
          ((u16*)C)[gr * N + gc] = f2bf(acc[mi][ni][r]);
        else
          ((float*)C)[gr * N + gc] = acc[mi][ni][r];
      }
}

// ---------------------------------------------------------------- elementwise
__global__ __launch_bounds__(256) void k_elem(
    const u16* __restrict__ rkv,      // [B, 3D] bf16: r | k | v
    const float* __restrict__ frac_n, const float* __restrict__ frac_d,
    const float* __restrict__ scale,
    const float* __restrict__ w_u, const float* __restrict__ w_w,
    float* __restrict__ o_nfn, float* __restrict__ o_nfd,
    float* __restrict__ o_ns,  u16* __restrict__ a_b) {
  const long idx4 = ((long)blockIdx.x * 256 + threadIdx.x) * 4;
  const int d = (int)(idx4 % D_SZ);
  const long rbase = (idx4 / D_SZ) * (3 * (long)D_SZ) + d;

  u16x4 r4 = *reinterpret_cast<const u16x4*>(rkv + rbase);
  u16x4 k4 = *reinterpret_cast<const u16x4*>(rkv + rbase + D_SZ);
  u16x4 v4 = *reinterpret_cast<const u16x4*>(rkv + rbase + 2 * D_SZ);
  f32x4 fn = *reinterpret_cast<const f32x4*>(frac_n + idx4);
  f32x4 fd = *reinterpret_cast<const f32x4*>(frac_d + idx4);
  f32x4 sc = *reinterpret_cast<const f32x4*>(scale + idx4);
  f32x4 wu = *reinterpret_cast<const f32x4*>(w_u + d);
  f32x4 ww = *reinterpret_cast<const f32x4*>(w_w + d);

  f32x4 onf, ond, ons; u16x4 oa;
#pragma unroll
  for (int j = 0; j < 4; ++j) {
    const float r = 1.0f / (1.0f + __expf(-bf2f(r4[j])));
    const float k = bf2f(k4[j]);
    const float v = bf2f(v4[j]);
    const float s = sc[j], n = fn[j], dn = fd[j];

    const float ss  = fmaxf(s, wu[j] + k);
    const float cm  = __expf(s - ss);
    const float am  = __expf(wu[j] + k - ss);
    const float fnt = cm * n + am * v;
    const float fdt = cm * dn + am;

    const float ns  = fmaxf(s + ww[j], k);
    const float ncm = __expf(s + ww[j] - ns);
    const float nam = __expf(k - ns);
    onf[j] = ncm * n + nam * v;
    ond[j] = ncm * dn + nam;
    ons[j] = ns;
    oa[j]  = f2bf(r * (fnt / fdt));
  }
  *reinterpret_cast<f32x4*>(o_nfn + idx4) = onf;
  *reinterpret_cast<f32x4*>(o_nfd + idx4) = ond;
  *reinterpret_cast<f32x4*>(o_ns  + idx4) = ons;
  *reinterpret_cast<u16x4*>(a_b   + idx4) = oa;
}

// ---------------------------------------------------------------- launch
extern "C" void kernel_launch(void* const* d_in, const int* in_sizes, int n_in,
                              void* d_out, int out_size, void* d_ws, size_t ws_size,
                              hipStream_t stream) {
  const float* x      = (const float*)d_in[0];
  const float* frac_n = (const float*)d_in[1];
  const float* frac_d = (const float*)d_in[2];
  const float* scale  = (const float*)d_in[3];
  const float* wr     = (const float*)d_in[4];
  const float* wk     = (const float*)d_in[5];
  const float* wv     = (const float*)d_in[6];
  const float* wo     = (const float*)d_in[7];
  const float* wu     = (const float*)d_in[8];
  const float* ww     = (const float*)d_in[9];
  float* out = (float*)d_out;

  u16* Xb   = (u16*)d_ws;        // BD
  u16* W3b  = Xb + BD;           // 3*DD  (w_r | w_k | w_v rows)
  u16* Wob  = W3b + 3 * DD;      // DD
  u16* rkvb = Wob + DD;          // 3*BD
  u16* ab   = rkvb + 3 * BD;     // BD

  // 1) fp32 -> bf16 conversions
  {
    const long total = BD + 4 * DD;             // 25165824
    const int blocks = (int)(total / 4 / 256);  // 24576 exact
    k_convert<<<blocks, 256, 0, stream>>>(x, wr, wk, wv, wo, Xb, W3b, Wob);
  }
  // 2) rkv = X @ [Wr;Wk;Wv]^T   [B, 3D] bf16   (8-phase 256^2, 1-D grid, XCD swizzle)
  k_gemm8<true><<<dim3((B_SZ / 256) * (3 * D_SZ / 256)), 512, 0, stream>>>(
      Xb, W3b, rkvb, B_SZ, 3 * D_SZ, D_SZ);
  // 3) elementwise
  k_elem<<<(int)(BD / 4 / 256), 256, 0, stream>>>(
      rkvb, frac_n, frac_d, scale, wu, ww,
      out + BD, out + 2 * BD, out + 3 * BD, ab);
  // 4) output = a @ Wo^T  -> d_out[0:BD] fp32  (m97 128^2, 512 blocks)
  k_gemm_bt<false><<<dim3(D_SZ / 128, B_SZ / 128), 256, 0, stream>>>(
      ab, Wob, out, B_SZ, D_SZ, D_SZ);
}

// Round 4
// 256.607 us; speedup vs baseline: 1.2160x; 1.2160x over previous
//
#include <hip/hip_runtime.h>
#include <hip/hip_bf16.h>
#include <stdint.h>

#define B_SZ 4096
#define D_SZ 2048

typedef __attribute__((ext_vector_type(4))) float f32x4;
typedef __attribute__((ext_vector_type(8))) __bf16 bf16x8;
typedef __attribute__((ext_vector_type(4))) unsigned short u16x4;
typedef unsigned short u16;

static constexpr long BD = (long)B_SZ * D_SZ;   // 8388608
static constexpr long DD = (long)D_SZ * D_SZ;   // 4194304

__device__ __forceinline__ u16 f2bf(float f) {
  union { float f; unsigned int u; } c; c.f = f;
  unsigned int u = c.u;
  u = (u + 0x7fffu + ((u >> 16) & 1u)) >> 16;
  return (u16)u;
}
__device__ __forceinline__ float bf2f(u16 h) {
  union { unsigned int u; float f; } c; c.u = ((unsigned int)h) << 16;
  return c.f;
}

// ---------------------------------------------------------------- convert
__global__ __launch_bounds__(256) void k_convert(
    const float* __restrict__ x,  const float* __restrict__ wr,
    const float* __restrict__ wk, const float* __restrict__ wv,
    const float* __restrict__ wo,
    u16* __restrict__ Xb, u16* __restrict__ W3b, u16* __restrict__ Wob) {
  long i = ((long)blockIdx.x * 256 + threadIdx.x) * 4;
  const float* src; u16* dst; long so, dofs;
  if (i < BD)               { src = x;  so = i;            dst = Xb;  dofs = so; }
  else if (i < BD + DD)     { src = wr; so = i - BD;       dst = W3b; dofs = i - BD; }
  else if (i < BD + 2*DD)   { src = wk; so = i - BD - DD;  dst = W3b; dofs = i - BD; }
  else if (i < BD + 3*DD)   { src = wv; so = i - BD - 2*DD; dst = W3b; dofs = i - BD; }
  else                      { src = wo; so = i - BD - 3*DD; dst = Wob; dofs = so; }
  f32x4 v = *reinterpret_cast<const f32x4*>(src + so);
  u16x4 o;
  o[0] = f2bf(v[0]); o[1] = f2bf(v[1]); o[2] = f2bf(v[2]); o[3] = f2bf(v[3]);
  *reinterpret_cast<u16x4*>(dst + dofs) = o;
}

// ---------------------------------------------------------------- async global->LDS
__device__ __forceinline__ void gload16(const u16* g, const u16* l) {
  __builtin_amdgcn_global_load_lds(
      (const __attribute__((address_space(1))) unsigned int*)g,
      (__attribute__((address_space(3))) unsigned int*)l, 16, 0, 0);
}

#define FENCE asm volatile("" ::: "memory")
#define BAR do { FENCE; __builtin_amdgcn_s_barrier(); FENCE; } while (0)
#define VMC(n) asm volatile("s_waitcnt vmcnt(" #n ")" ::: "memory")

// ================================================================ 8-phase 256x256 GEMM
// C = A * B^T.  A:[M,K] bf16 rm, Bm:[N,K] bf16 rm. BK=64, 512 thr = 8 waves (2M x 4N).
// Deep-prefetch schedule: stages consolidated at S3/S4/S7/S8, 16 loads in flight,
// VMC(8) at S4/S8 tails -> every wait targets loads issued 5-6 slots earlier.
// Region safety: B-halves of a buffer are last read at S2/S6, restaged at S3/S7;
// A-halves last read at S3/S7 (row-split across wm), restaged at S4/S8. All stage
// issues are after a barrier that follows completion of the region's last reads.
template <bool OUT_BF16>
__global__ __launch_bounds__(512, 2) void k_gemm8(
    const u16* __restrict__ A, const u16* __restrict__ Bm,
    void* __restrict__ C, int M, int N, int K) {
  __shared__ __align__(16) u16 lds[65536];  // 128 KiB
  const int tid = threadIdx.x;
  const int l   = tid & 63;
  const int wv  = tid >> 6;   // 0..7
  const int wm  = wv >> 2;    // 0..1
  const int wn  = wv & 3;     // 0..3
  const int bm = blockIdx.y, bn = blockIdx.x;
  const int NT = K >> 6;      // 64-wide K-tiles; NT even, >=4

  // ---- staging addressing (inverse-swizzled global source, linear LDS dest)
  const int gcol = (((l & 7) ^ (l >> 3)) << 3);       // element col, pre-swizzled
  const int grow = wv * 16 + (l >> 3);                // j=0 row within half (j=1: +8)
  const u16* Abase = A  + (long)(bm * 256 + grow) * K + gcol;
  const u16* Bbase = Bm + (long)(bn * 256 + grow) * K + gcol;
  const int stdst = wv * 1024;                        // u16 idx within region (+512 for j=1)

  // STAGE(t, hk): hk 0=B-h0, 1=B-h1, 2=A-h0, 3=A-h1  (2 loads/wave each)
  #define STAGE(t, hk) do {                                                  \
    const int  _h   = (hk) & 1;                                              \
    const bool _isA = (hk) >= 2;                                             \
    const u16* _g = (_isA ? Abase : Bbase) + (long)(_h * 128) * K + (long)(t) * 64; \
    u16* _d = &lds[((t) & 1) * 32768 + (_isA ? 0 : 16384) + _h * 8192 + stdst]; \
    gload16(_g, _d);                                                         \
    gload16(_g + 8 * (long)K, _d + 512);                                     \
  } while (0)

  // ---- read-side addressing (swizzled)
  const int rby  = (l & 15) * 128;                          // row byte
  const int obx0 = ((l >> 4) * 16) ^ ((l & 7) << 4);        // ks=0 byte-in-row
  int laneO[2];
  laneO[0] = (rby + obx0) >> 1;          // u16 idx
  laneO[1] = laneO[0] ^ 32;              // ks=1 (= byte ^ 64)

  f32x4 acc[8][4] = {};
  bf16x8 af[4][2], bf01[2][2], bf23[2][2];

  auto LDA = [&](int p, int mbase) {
#pragma unroll
    for (int mi = 0; mi < 4; ++mi)
#pragma unroll
      for (int ks = 0; ks < 2; ++ks)
        af[mi][ks] = *reinterpret_cast<const bf16x8*>(
            &lds[p * 32768 + wm * 8192 + (mbase + mi) * 1024 + laneO[ks]]);
  };
  auto LDB = [&](int p, int nbase, bf16x8 (&bf)[2][2]) {
#pragma unroll
    for (int ni = 0; ni < 2; ++ni)
#pragma unroll
      for (int ks = 0; ks < 2; ++ks)
        bf[ni][ks] = *reinterpret_cast<const bf16x8*>(
            &lds[p * 32768 + 16384 + wn * 4096 + (nbase + ni) * 1024 + laneO[ks]]);
  };
  // ks-outer: same-acc reuse distance = 8 MFMAs
  auto MQ = [&](int mbase, int nbase, bf16x8 (&bf)[2][2]) {
    __builtin_amdgcn_s_setprio(1);
#pragma unroll
    for (int ks = 0; ks < 2; ++ks)
#pragma unroll
      for (int mi = 0; mi < 4; ++mi)
#pragma unroll
        for (int ni = 0; ni < 2; ++ni)
          acc[mbase + mi][nbase + ni] = __builtin_amdgcn_mfma_f32_16x16x32_bf16(
              af[mi][ks], bf[ni][ks], acc[mbase + mi][nbase + ni], 0, 0, 0);
    __builtin_amdgcn_s_setprio(0);
  };

  // ---- prologue: stage tiles 0 and 1 fully (16 loads); prove tile0; 8 in flight
  STAGE(0, 0); STAGE(0, 1); STAGE(0, 2); STAGE(0, 3);
  STAGE(1, 0); STAGE(1, 1); STAGE(1, 2); STAGE(1, 3);
  VMC(8); BAR;

  // ---- main loop: 2 K-tiles / iteration, 8 slots
  // invariant entering S1: tile t resident & proven; t+1's 8 loads outstanding
  int t = 0;
  for (; t + 3 < NT; t += 2) {
    // S1
    LDA(0, 0); LDB(0, 0, bf01); BAR;
    MQ(0, 0, bf01); BAR;
    // S2
    LDB(0, 2, bf23); BAR;
    MQ(0, 2, bf23); BAR;
    // S3  (buf0 B-halves free after S2 -> restage for t+2)
    LDA(0, 4); STAGE(t + 2, 0); STAGE(t + 2, 1); BAR;
    MQ(4, 2, bf23); BAR;
    // S4  (buf0 A-halves free after S3 -> restage; prove t+1: drains 8 oldest)
    STAGE(t + 2, 2); STAGE(t + 2, 3); VMC(8); BAR;
    MQ(4, 0, bf01); BAR;
    // S5
    LDA(1, 0); LDB(1, 0, bf01); BAR;
    MQ(0, 0, bf01); BAR;
    // S6
    LDB(1, 2, bf23); BAR;
    MQ(0, 2, bf23); BAR;
    // S7
    LDA(1, 4); STAGE(t + 3, 0); STAGE(t + 3, 1); BAR;
    MQ(4, 2, bf23); BAR;
    // S8  (prove t+2 for next iteration's S1)
    STAGE(t + 3, 2); STAGE(t + 3, 3); VMC(8); BAR;
    MQ(4, 0, bf01); BAR;
  }

  // ---- epilogue: tiles NT-2 (buf0), NT-1 (buf1); NT-1's loads outstanding
  // E1
  LDA(0, 0); LDB(0, 0, bf01); BAR;
  MQ(0, 0, bf01); BAR;
  // E2
  LDB(0, 2, bf23); BAR;
  MQ(0, 2, bf23); BAR;
  // E3
  LDA(0, 4); BAR;
  MQ(4, 2, bf23); BAR;
  // E4
  VMC(0); BAR;
  MQ(4, 0, bf01); BAR;
  // E5
  LDA(1, 0); LDB(1, 0, bf01); BAR;
  MQ(0, 0, bf01); BAR;
  // E6
  LDB(1, 2, bf23); BAR;
  MQ(0, 2, bf23); BAR;
  // E7
  LDA(1, 4); BAR;
  MQ(4, 2, bf23); BAR;
  // E8
  MQ(4, 0, bf01);
  #undef STAGE

  // ---- C write: 16x16 frag layout col = l&15, row = (l>>4)*4 + reg
  const int rb = (l >> 4) * 4, cb = l & 15;
  const long Crow0 = (long)bm * 256 + wm * 128 + rb;
  const long Ccol0 = (long)bn * 256 + wn * 64 + cb;
#pragma unroll
  for (int mf = 0; mf < 8; ++mf)
#pragma unroll
    for (int nf = 0; nf < 4; ++nf)
#pragma unroll
      for (int r = 0; r < 4; ++r) {
        const long gr = Crow0 + mf * 16 + r;
        const long gc = Ccol0 + nf * 16;
        if constexpr (OUT_BF16)
          ((u16*)C)[gr * N + gc] = f2bf(acc[mf][nf][r]);
        else
          ((float*)C)[gr * N + gc] = acc[mf][nf][r];
      }
}

// ---------------------------------------------------------------- m97 128x128 GEMM (out-proj)
template <bool OUT_BF16>
__global__ __launch_bounds__(256) void k_gemm_bt(
    const u16* __restrict__ A, const u16* __restrict__ Bm,
    void* __restrict__ C, int M, int N, int K) {
  __shared__ __align__(16) u16 As[128 * 32];
  __shared__ __align__(16) u16 Bs[128 * 32];
  const int tid  = threadIdx.x;
  const int lane = tid & 63;
  const int wave = tid >> 6;
  const int bm = blockIdx.y, bn = blockIdx.x;
  const int wm = (wave >> 1) * 64, wn = (wave & 1) * 64;

  f32x4 acc[4][4] = {};

  const int row0 = tid >> 2;
  const int cole = (tid & 3) * 8;
  const u16* Ag = A + (long)(bm * 128 + row0) * K + cole;
  const u16* Bg = Bm + (long)(bn * 128 + row0) * K + cole;
  const u16* AsW = As + wave * 512;
  const u16* BsW = Bs + wave * 512;

  const int fr = lane & 15;
  const int fk = (lane >> 4) * 8;

  for (int k0 = 0; k0 < K; k0 += 32) {
    gload16(Ag + k0,           AsW);
    gload16(Ag + 64 * K + k0,  AsW + 2048);
    gload16(Bg + k0,           BsW);
    gload16(Bg + 64 * K + k0,  BsW + 2048);
    __syncthreads();

    bf16x8 af[4], bf[4];
#pragma unroll
    for (int mi = 0; mi < 4; ++mi)
      af[mi] = *reinterpret_cast<const bf16x8*>(&As[(wm + mi * 16 + fr) * 32 + fk]);
#pragma unroll
    for (int ni = 0; ni < 4; ++ni)
      bf[ni] = *reinterpret_cast<const bf16x8*>(&Bs[(wn + ni * 16 + fr) * 32 + fk]);
#pragma unroll
    for (int mi = 0; mi < 4; ++mi)
#pragma unroll
      for (int ni = 0; ni < 4; ++ni)
        acc[mi][ni] = __builtin_amdgcn_mfma_f32_16x16x32_bf16(af[mi], bf[ni], acc[mi][ni], 0, 0, 0);
    __syncthreads();
  }

  const int rb = (lane >> 4) * 4, cb = lane & 15;
  const long Crow0 = (long)bm * 128 + wm + rb;
  const long Ccol0 = (long)bn * 128 + wn + cb;
#pragma unroll
  for (int mi = 0; mi < 4; ++mi)
#pragma unroll
    for (int ni = 0; ni < 4; ++ni)
#pragma unroll
      for (int r = 0; r < 4; ++r) {
        const long gr = Crow0 + mi * 16 + r;
        const long gc = Ccol0 + ni * 16;
        if constexpr (OUT_BF16)
          ((u16*)C)[gr * N + gc] = f2bf(acc[mi][ni][r]);
        else
          ((float*)C)[gr * N + gc] = acc[mi][ni][r];
      }
}

// ---------------------------------------------------------------- elementwise
__global__ __launch_bounds__(256) void k_elem(
    const u16* __restrict__ rkv,      // [B, 3D] bf16: r | k | v
    const float* __restrict__ frac_n, const float* __restrict__ frac_d,
    const float* __restrict__ scale,
    const float* __restrict__ w_u, const float* __restrict__ w_w,
    float* __restrict__ o_nfn, float* __restrict__ o_nfd,
    float* __restrict__ o_ns,  u16* __restrict__ a_b) {
  const long idx4 = ((long)blockIdx.x * 256 + threadIdx.x) * 4;
  const int d = (int)(idx4 % D_SZ);
  const long rbase = (idx4 / D_SZ) * (3 * (long)D_SZ) + d;

  u16x4 r4 = *reinterpret_cast<const u16x4*>(rkv + rbase);
  u16x4 k4 = *reinterpret_cast<const u16x4*>(rkv + rbase + D_SZ);
  u16x4 v4 = *reinterpret_cast<const u16x4*>(rkv + rbase + 2 * D_SZ);
  f32x4 fn = *reinterpret_cast<const f32x4*>(frac_n + idx4);
  f32x4 fd = *reinterpret_cast<const f32x4*>(frac_d + idx4);
  f32x4 sc = *reinterpret_cast<const f32x4*>(scale + idx4);
  f32x4 wu = *reinterpret_cast<const f32x4*>(w_u + d);
  f32x4 ww = *reinterpret_cast<const f32x4*>(w_w + d);

  f32x4 onf, ond, ons; u16x4 oa;
#pragma unroll
  for (int j = 0; j < 4; ++j) {
    const float r = 1.0f / (1.0f + __expf(-bf2f(r4[j])));
    const float k = bf2f(k4[j]);
    const float v = bf2f(v4[j]);
    const float s = sc[j], n = fn[j], dn = fd[j];

    const float ss  = fmaxf(s, wu[j] + k);
    const float cm  = __expf(s - ss);
    const float am  = __expf(wu[j] + k - ss);
    const float fnt = cm * n + am * v;
    const float fdt = cm * dn + am;

    const float ns  = fmaxf(s + ww[j], k);
    const float ncm = __expf(s + ww[j] - ns);
    const float nam = __expf(k - ns);
    onf[j] = ncm * n + nam * v;
    ond[j] = ncm * dn + nam;
    ons[j] = ns;
    oa[j]  = f2bf(r * (fnt / fdt));
  }
  *reinterpret_cast<f32x4*>(o_nfn + idx4) = onf;
  *reinterpret_cast<f32x4*>(o_nfd + idx4) = ond;
  *reinterpret_cast<f32x4*>(o_ns  + idx4) = ons;
  *reinterpret_cast<u16x4*>(a_b   + idx4) = oa;
}

// ---------------------------------------------------------------- launch
extern "C" void kernel_launch(void* const* d_in, const int* in_sizes, int n_in,
                              void* d_out, int out_size, void* d_ws, size_t ws_size,
                              hipStream_t stream) {
  const float* x      = (const float*)d_in[0];
  const float* frac_n = (const float*)d_in[1];
  const float* frac_d = (const float*)d_in[2];
  const float* scale  = (const float*)d_in[3];
  const float* wr     = (const float*)d_in[4];
  const float* wk     = (const float*)d_in[5];
  const float* wv     = (const float*)d_in[6];
  const float* wo     = (const float*)d_in[7];
  const float* wu     = (const float*)d_in[8];
  const float* ww     = (const float*)d_in[9];
  float* out = (float*)d_out;

  u16* Xb   = (u16*)d_ws;        // BD
  u16* W3b  = Xb + BD;           // 3*DD  (w_r | w_k | w_v rows)
  u16* Wob  = W3b + 3 * DD;      // DD
  u16* rkvb = Wob + DD;          // 3*BD
  u16* ab   = rkvb + 3 * BD;     // BD

  // 1) fp32 -> bf16 conversions
  {
    const long total = BD + 4 * DD;             // 25165824
    const int blocks = (int)(total / 4 / 256);  // 24576 exact
    k_convert<<<blocks, 256, 0, stream>>>(x, wr, wk, wv, wo, Xb, W3b, Wob);
  }
  // 2) rkv = X @ [Wr;Wk;Wv]^T   [B, 3D] bf16   (8-phase 256^2, deep prefetch)
  k_gemm8<true><<<dim3(3 * D_SZ / 256, B_SZ / 256), 512, 0, stream>>>(
      Xb, W3b, rkvb, B_SZ, 3 * D_SZ, D_SZ);
  // 3) elementwise
  k_elem<<<(int)(BD / 4 / 256), 256, 0, stream>>>(
      rkvb, frac_n, frac_d, scale, wu, ww,
      out + BD, out + 2 * BD, out + 3 * BD, ab);
  // 4) output = a @ Wo^T  -> d_out[0:BD] fp32  (m97 128^2, 512 blocks)
  k_gemm_bt<false><<<dim3(D_SZ / 128, B_SZ / 128), 256, 0, stream>>>(
      ab, Wob, out, B_SZ, D_SZ, D_SZ);
}

// Round 5
// 220.622 us; speedup vs baseline: 1.4143x; 1.1631x over previous
//
#include <hip/hip_runtime.h>
#include <hip/hip_bf16.h>
#include <stdint.h>

#define B_SZ 4096
#define D_SZ 2048

typedef __attribute__((ext_vector_type(4))) float f32x4;
typedef __attribute__((ext_vector_type(8))) __bf16 bf16x8;
typedef __attribute__((ext_vector_type(4))) unsigned short u16x4;
typedef unsigned short u16;

static constexpr long BD = (long)B_SZ * D_SZ;   // 8388608
static constexpr long DD = (long)D_SZ * D_SZ;   // 4194304

__device__ __forceinline__ u16 f2bf(float f) {
  union { float f; unsigned int u; } c; c.f = f;
  unsigned int u = c.u;
  u = (u + 0x7fffu + ((u >> 16) & 1u)) >> 16;
  return (u16)u;
}
__device__ __forceinline__ float bf2f(u16 h) {
  union { unsigned int u; float f; } c; c.u = ((unsigned int)h) << 16;
  return c.f;
}

// ---------------------------------------------------------------- convert
__global__ __launch_bounds__(256) void k_convert(
    const float* __restrict__ x,  const float* __restrict__ wr,
    const float* __restrict__ wk, const float* __restrict__ wv,
    const float* __restrict__ wo,
    u16* __restrict__ Xb, u16* __restrict__ W3b, u16* __restrict__ Wob) {
  long i = ((long)blockIdx.x * 256 + threadIdx.x) * 4;
  const float* src; u16* dst; long so, dofs;
  if (i < BD)               { src = x;  so = i;            dst = Xb;  dofs = so; }
  else if (i < BD + DD)     { src = wr; so = i - BD;       dst = W3b; dofs = i - BD; }
  else if (i < BD + 2*DD)   { src = wk; so = i - BD - DD;  dst = W3b; dofs = i - BD; }
  else if (i < BD + 3*DD)   { src = wv; so = i - BD - 2*DD; dst = W3b; dofs = i - BD; }
  else                      { src = wo; so = i - BD - 3*DD; dst = Wob; dofs = so; }
  f32x4 v = *reinterpret_cast<const f32x4*>(src + so);
  u16x4 o;
  o[0] = f2bf(v[0]); o[1] = f2bf(v[1]); o[2] = f2bf(v[2]); o[3] = f2bf(v[3]);
  *reinterpret_cast<u16x4*>(dst + dofs) = o;
}

// ---------------------------------------------------------------- async global->LDS
__device__ __forceinline__ void gload16(const u16* g, const u16* l) {
  __builtin_amdgcn_global_load_lds(
      (const __attribute__((address_space(1))) unsigned int*)g,
      (__attribute__((address_space(3))) unsigned int*)l, 16, 0, 0);
}

#define FENCE asm volatile("" ::: "memory")
#define BAR do { FENCE; __builtin_amdgcn_s_barrier(); FENCE; } while (0)
#define VMC(n) asm volatile("s_waitcnt vmcnt(" #n ")" ::: "memory")

// ================================================================ 128x128 GEMM, BK=64
// C = A * B^T.  A:[M,K] bf16 rm, Bm:[N,K] bf16 rm.
// 256 threads = 4 waves (2M x 2N), wave tile 64x64, acc = 4x4 f32x4 = 64 VGPR.
// LDS 64 KiB (2 bufs x (A 16K + B 16K)) -> 2 blocks/CU co-resident: independent
// barrier domains overlap one block's LDS/stage window with the other's MFMA.
// T2 XOR-swizzle byte^=((row&7)<<4) via inverse-swizzled global source (linear LDS).
// 2-phase counted schedule: STAGE(t+1) -> frag reads + MFMA(t) -> vmcnt(0) + BAR.
template <bool OUT_BF16>
__global__ __launch_bounds__(256, 4) void k_gemm128(
    const u16* __restrict__ A, const u16* __restrict__ Bm,
    void* __restrict__ C, int M, int N, int K) {
  __shared__ __align__(16) u16 lds[32768];  // 64 KiB
  const int tid = threadIdx.x;
  const int l   = tid & 63;
  const int w   = tid >> 6;     // 0..3
  const int wm  = w >> 1, wn = w & 1;
  const int bm = blockIdx.y, bn = blockIdx.x;
  const int NT = K >> 6;        // >= 2

  // ---- staging: wave w stages rows [w*32, w*32+32) of A and of B (4 chunks of 8 rows)
  const int gcol  = (((l & 7) ^ (l >> 3)) << 3);   // inverse-swizzled element col
  const int grow  = w * 32 + (l >> 3);             // row within 128-row tile (chunk c: +8c)
  const u16* Abase = A  + (long)(bm * 128 + grow) * K + gcol;
  const u16* Bbase = Bm + (long)(bn * 128 + grow) * K + gcol;
  const int sdst = w * 2048;                       // u16 offset within A/B region

  // lds u16 map: buf p at p*16384; A at +0 (128r x 64c), B at +8192
  #define STAGE(t) do {                                              \
    const long _ko = (long)(t) * 64;                                 \
    u16* _da = &lds[((t) & 1) * 16384 + sdst];                       \
    u16* _db = _da + 8192;                                           \
    _Pragma("unroll")                                                \
    for (int _c = 0; _c < 4; ++_c) {                                 \
      gload16(Abase + (long)_c * 8 * K + _ko, _da + _c * 512);       \
      gload16(Bbase + (long)_c * 8 * K + _ko, _db + _c * 512);       \
    }                                                                \
  } while (0)

  // ---- read-side addressing (swizzled): row = l&15 within frag, k-half = l>>4
  const int rby  = (l & 15) * 128;                       // row byte (row stride 128B)
  const int obx0 = ((l >> 4) * 16) ^ ((l & 7) << 4);     // ks=0 byte-in-row
  const int lo0  = (rby + obx0) >> 1;                    // u16 index
  const int lo1  = lo0 ^ 32;                             // ks=1 (byte ^ 64)

  f32x4 acc[4][4] = {};

  // one K-tile's compute from buffer p
  auto COMPUTE = [&](int p) {
#pragma unroll
    for (int ks = 0; ks < 2; ++ks) {
      const int lo = ks ? lo1 : lo0;
      bf16x8 af[4], bf[4];
#pragma unroll
      for (int mi = 0; mi < 4; ++mi)
        af[mi] = *reinterpret_cast<const bf16x8*>(
            &lds[p * 16384 + (wm * 4 + mi) * 1024 + lo]);
#pragma unroll
      for (int ni = 0; ni < 4; ++ni)
        bf[ni] = *reinterpret_cast<const bf16x8*>(
            &lds[p * 16384 + 8192 + (wn * 4 + ni) * 1024 + lo]);
      __builtin_amdgcn_s_setprio(1);
#pragma unroll
      for (int mi = 0; mi < 4; ++mi)
#pragma unroll
        for (int ni = 0; ni < 4; ++ni)
          acc[mi][ni] = __builtin_amdgcn_mfma_f32_16x16x32_bf16(
              af[mi], bf[ni], acc[mi][ni], 0, 0, 0);
      __builtin_amdgcn_s_setprio(0);
    }
  };

  // ---- prologue: stage tile 0, prove, sync
  STAGE(0);
  VMC(0); BAR;

  // ---- main loop: stage next while computing current; prove at tail
  for (int t = 0; t < NT - 1; ++t) {
    STAGE(t + 1);
    COMPUTE(t & 1);
    VMC(0); BAR;
  }
  // ---- last tile
  COMPUTE((NT - 1) & 1);
  #undef STAGE

  // ---- C write: 16x16 frag layout col = l&15, row = (l>>4)*4 + reg
  const int rb = (l >> 4) * 4, cb = l & 15;
  const long Crow0 = (long)bm * 128 + wm * 64 + rb;
  const long Ccol0 = (long)bn * 128 + wn * 64 + cb;
#pragma unroll
  for (int mi = 0; mi < 4; ++mi)
#pragma unroll
    for (int ni = 0; ni < 4; ++ni)
#pragma unroll
      for (int r = 0; r < 4; ++r) {
        const long gr = Crow0 + mi * 16 + r;
        const long gc = Ccol0 + ni * 16;
        if constexpr (OUT_BF16)
          ((u16*)C)[gr * N + gc] = f2bf(acc[mi][ni][r]);
        else
          ((float*)C)[gr * N + gc] = acc[mi][ni][r];
      }
}

// ---------------------------------------------------------------- elementwise
__global__ __launch_bounds__(256) void k_elem(
    const u16* __restrict__ rkv,      // [B, 3D] bf16: r | k | v
    const float* __restrict__ frac_n, const float* __restrict__ frac_d,
    const float* __restrict__ scale,
    const float* __restrict__ w_u, const float* __restrict__ w_w,
    float* __restrict__ o_nfn, float* __restrict__ o_nfd,
    float* __restrict__ o_ns,  u16* __restrict__ a_b) {
  const long idx4 = ((long)blockIdx.x * 256 + threadIdx.x) * 4;
  const int d = (int)(idx4 % D_SZ);
  const long rbase = (idx4 / D_SZ) * (3 * (long)D_SZ) + d;

  u16x4 r4 = *reinterpret_cast<const u16x4*>(rkv + rbase);
  u16x4 k4 = *reinterpret_cast<const u16x4*>(rkv + rbase + D_SZ);
  u16x4 v4 = *reinterpret_cast<const u16x4*>(rkv + rbase + 2 * D_SZ);
  f32x4 fn = *reinterpret_cast<const f32x4*>(frac_n + idx4);
  f32x4 fd = *reinterpret_cast<const f32x4*>(frac_d + idx4);
  f32x4 sc = *reinterpret_cast<const f32x4*>(scale + idx4);
  f32x4 wu = *reinterpret_cast<const f32x4*>(w_u + d);
  f32x4 ww = *reinterpret_cast<const f32x4*>(w_w + d);

  f32x4 onf, ond, ons; u16x4 oa;
#pragma unroll
  for (int j = 0; j < 4; ++j) {
    const float r = 1.0f / (1.0f + __expf(-bf2f(r4[j])));
    const float k = bf2f(k4[j]);
    const float v = bf2f(v4[j]);
    const float s = sc[j], n = fn[j], dn = fd[j];

    const float ss  = fmaxf(s, wu[j] + k);
    const float cm  = __expf(s - ss);
    const float am  = __expf(wu[j] + k - ss);
    const float fnt = cm * n + am * v;
    const float fdt = cm * dn + am;

    const float ns  = fmaxf(s + ww[j], k);
    const float ncm = __expf(s + ww[j] - ns);
    const float nam = __expf(k - ns);
    onf[j] = ncm * n + nam * v;
    ond[j] = ncm * dn + nam;
    ons[j] = ns;
    oa[j]  = f2bf(r * (fnt / fdt));
  }
  *reinterpret_cast<f32x4*>(o_nfn + idx4) = onf;
  *reinterpret_cast<f32x4*>(o_nfd + idx4) = ond;
  *reinterpret_cast<f32x4*>(o_ns  + idx4) = ons;
  *reinterpret_cast<u16x4*>(a_b   + idx4) = oa;
}

// ---------------------------------------------------------------- launch
extern "C" void kernel_launch(void* const* d_in, const int* in_sizes, int n_in,
                              void* d_out, int out_size, void* d_ws, size_t ws_size,
                              hipStream_t stream) {
  const float* x      = (const float*)d_in[0];
  const float* frac_n = (const float*)d_in[1];
  const float* frac_d = (const float*)d_in[2];
  const float* scale  = (const float*)d_in[3];
  const float* wr     = (const float*)d_in[4];
  const float* wk     = (const float*)d_in[5];
  const float* wv     = (const float*)d_in[6];
  const float* wo     = (const float*)d_in[7];
  const float* wu     = (const float*)d_in[8];
  const float* ww     = (const float*)d_in[9];
  float* out = (float*)d_out;

  u16* Xb   = (u16*)d_ws;        // BD
  u16* W3b  = Xb + BD;           // 3*DD  (w_r | w_k | w_v rows)
  u16* Wob  = W3b + 3 * DD;      // DD
  u16* rkvb = Wob + DD;          // 3*BD
  u16* ab   = rkvb + 3 * BD;     // BD

  // 1) fp32 -> bf16 conversions
  {
    const long total = BD + 4 * DD;             // 25165824
    const int blocks = (int)(total / 4 / 256);  // 24576 exact
    k_convert<<<blocks, 256, 0, stream>>>(x, wr, wk, wv, wo, Xb, W3b, Wob);
  }
  // 2) rkv = X @ [Wr;Wk;Wv]^T   [B, 3D] bf16
  //    grid 48x32 = 1536 blocks = exactly 3 rounds at 2 blocks/CU
  k_gemm128<true><<<dim3(3 * D_SZ / 128, B_SZ / 128), 256, 0, stream>>>(
      Xb, W3b, rkvb, B_SZ, 3 * D_SZ, D_SZ);
  // 3) elementwise
  k_elem<<<(int)(BD / 4 / 256), 256, 0, stream>>>(
      rkvb, frac_n, frac_d, scale, wu, ww,
      out + BD, out + 2 * BD, out + 3 * BD, ab);
  // 4) output = a @ Wo^T  -> d_out[0:BD] fp32
  //    grid 16x32 = 512 blocks = exactly 1 round at 2 blocks/CU
  k_gemm128<false><<<dim3(D_SZ / 128, B_SZ / 128), 256, 0, stream>>>(
      ab, Wob, out, B_SZ, D_SZ, D_SZ);
}